// Round 6
// baseline (3022.003 us; speedup 1.0000x reference)
//
#include <hip/hip_runtime.h>
#include <float.h>

#define NS 1536
#define DD 64

// ws layout (float elements)
static const size_t OFF_A  = 0;                          // A = h_sat + b1: [1536][64]
static const size_t OFF_C2 = 98304;                      // C2 = h_uav transposed [16][1536][4]
static const size_t OFF_L  = 196608;                     // logits [1536][1536]
static const size_t OFF_AS = 196608 + (size_t)NS * NS;   // int assign [1536]
// top_idx (ushort, 1536*256 = 786432 B) ALIASES the A/C2 region (dead after kB).

// ---------------- Kernel A: first-layer projections ----------------
__global__ __launch_bounds__(64) void kA(const float* __restrict__ sat,
                                         const float* __restrict__ uav,
                                         const float* __restrict__ W1,
                                         const float* __restrict__ b1,
                                         float* __restrict__ A,
                                         float* __restrict__ C2) {
    const int row = blockIdx.x;
    const int d = threadIdx.x;
    float accA = b1[d];
    float accC = 0.f;
    const float* __restrict__ satr = sat + row * DD;
    const float* __restrict__ uavr = uav + row * DD;
#pragma unroll 8
    for (int k = 0; k < DD; ++k) {
        accA = fmaf(satr[k], W1[k * DD + d], accA);
        accC = fmaf(uavr[k], W1[(DD + k) * DD + d], accC);
    }
    A[row * DD + d] = accA;
    C2[((size_t)(d >> 2) * NS + row) * 4 + (d & 3)] = accC;
}

// ---------------- Kernel B: all-pairs logits ----------------
__global__ __launch_bounds__(256) void kB(const float* __restrict__ A,
                                          const float* __restrict__ C2,
                                          const float* __restrict__ W2,
                                          const float* __restrict__ b2,
                                          const float* __restrict__ W3,
                                          float* __restrict__ L) {
    const int lane = threadIdx.x & 63;
    const int wave = threadIdx.x >> 6;
    const int i = __builtin_amdgcn_readfirstlane(blockIdx.x * 4 + wave);
    const int jbase = blockIdx.y * 256;
    const float* __restrict__ Ar = A + (size_t)i * DD;

    float u[4][32];
#pragma unroll
    for (int o = 0; o < 32; ++o) {
        const float b = b2[o];
        u[0][o] = b; u[1][o] = b; u[2][o] = b; u[3][o] = b;
    }

    const float4* __restrict__ C2v = (const float4*)C2;

    for (int d4 = 0; d4 < 16; ++d4) {
        float c[4][4];
#pragma unroll
        for (int p = 0; p < 4; ++p) {
            const float4 t = C2v[(size_t)d4 * NS + jbase + p * 64 + lane];
            c[p][0] = t.x; c[p][1] = t.y; c[p][2] = t.z; c[p][3] = t.w;
        }
#pragma unroll
        for (int dd = 0; dd < 4; ++dd) {
            const float a = Ar[d4 * 4 + dd];
            const float v0 = fmaxf(a + c[0][dd], 0.f);
            const float v1 = fmaxf(a + c[1][dd], 0.f);
            const float v2 = fmaxf(a + c[2][dd], 0.f);
            const float v3 = fmaxf(a + c[3][dd], 0.f);
            const float* __restrict__ w2r = W2 + (d4 * 4 + dd) * 32;
#pragma unroll
            for (int o = 0; o < 32; ++o) {
                const float w = w2r[o];
                u[0][o] = fmaf(v0, w, u[0][o]);
                u[1][o] = fmaf(v1, w, u[1][o]);
                u[2][o] = fmaf(v2, w, u[2][o]);
                u[3][o] = fmaf(v3, w, u[3][o]);
            }
        }
    }

#pragma unroll
    for (int p = 0; p < 4; ++p) {
        float acc = 0.f;
#pragma unroll
        for (int o = 0; o < 32; ++o)
            acc = fmaf(fmaxf(u[p][o], 0.f), W3[o], acc);
        L[(size_t)i * NS + jbase + p * 64 + lane] = acc;
    }
}

// ---------------- Kernel C: per-row sorted top-256 via 16-bit radix ----------------
// Output: top[row*256 + rank] = col (ushort), rank-major, sorted val desc / col asc.
__global__ __launch_bounds__(256) void kC(const float* __restrict__ L,
                                          unsigned short* __restrict__ top) {
    __shared__ int hist[256];
    __shared__ int suff[256];
    __shared__ float cv[1024];
    __shared__ int ci[1024];
    __shared__ int s_cnt, s_B0, s_base, s_B1;
    const int t = threadIdx.x;
    const int row = blockIdx.x;
    const float* __restrict__ Lr = L + (size_t)row * NS;

    top[row * 256 + t] = 0xFFFFu;   // sentinel (degenerate rows -> kD fallback)

    hist[t] = 0;
    if (t == 0) s_cnt = 0;
    __syncthreads();

    unsigned ub[6]; float fv[6];
#pragma unroll
    for (int k = 0; k < 6; ++k) {
        const float x = Lr[t + 256 * k];
        fv[k] = x;
        unsigned b = __float_as_uint(x);
        b = (b & 0x80000000u) ? ~b : (b | 0x80000000u);
        ub[k] = b;
        atomicAdd(&hist[b >> 24], 1);
    }
    __syncthreads();

    suff[t] = hist[t];
    __syncthreads();
    for (int off = 1; off < 256; off <<= 1) {
        const int v = (t + off < 256) ? suff[t + off] : 0;
        __syncthreads();
        suff[t] += v;
        __syncthreads();
    }
    if (suff[t] >= 256 && (t == 255 || suff[t + 1] < 256)) {
        s_B0 = t;
        s_base = (t == 255) ? 0 : suff[t + 1];
    }
    __syncthreads();
    const unsigned B0 = (unsigned)s_B0;
    const int base = s_base;

    hist[t] = 0;
    __syncthreads();
#pragma unroll
    for (int k = 0; k < 6; ++k)
        if ((ub[k] >> 24) == B0) atomicAdd(&hist[(ub[k] >> 16) & 255], 1);
    __syncthreads();
    suff[t] = hist[t];
    __syncthreads();
    for (int off = 1; off < 256; off <<= 1) {
        const int v = (t + off < 256) ? suff[t + off] : 0;
        __syncthreads();
        suff[t] += v;
        __syncthreads();
    }
    const int need = 256 - base;
    if (suff[t] >= need && (t == 255 || suff[t + 1] < need)) s_B1 = t;
    __syncthreads();
    const unsigned B1 = (unsigned)s_B1;
    const int m = base + suff[B1];
    if (m > 1024) return;

#pragma unroll
    for (int k = 0; k < 6; ++k) {
        const unsigned hi = ub[k] >> 24;
        const unsigned mid = (ub[k] >> 16) & 255u;
        if (hi > B0 || (hi == B0 && mid >= B1)) {
            const int pos = atomicAdd(&s_cnt, 1);
            cv[pos] = fv[k];
            ci[pos] = t + 256 * k;
        }
    }
    __syncthreads();

    for (int e = t; e < m; e += 256) {
        const float v = cv[e]; const int id = ci[e];
        int r = 0;
        for (int s2 = 0; s2 < m; ++s2) {
            const float vs = cv[s2];
            if (vs > v || (vs == v && ci[s2] < id)) ++r;
        }
        if (r < 256) top[row * 256 + r] = (unsigned short)id;
    }
}

// ---------------- Kernel D: block-sequential Gale-Shapley, single wave ----------------
// DA == serial greedy when all columns prefer the lowest row (unique stable
// matching; validated end-to-end in R5). Lane r owns row 64g+r of block g.
// holder[col] = lowest proposing row (atomicMin, monotone). Blocks processed
// sequentially, so prior blocks are immutable; within a block the lowest
// active lane settles permanently each round => <=64 rounds/block. Single
// wave => one serial instruction stream: no races, no barriers. Candidate
// holder-flags read 8 at a time (static addresses); next block's candidate
// uint4 prefetched during current block. Rows exhausting their top-256 list
// propose via masked argmax over holder[col] > row (== not-yet-rejected set,
// by holder monotonicity).
__global__ __launch_bounds__(64) void kD(const float* __restrict__ L,
                                         const unsigned short* __restrict__ top,
                                         int* __restrict__ assign) {
    __shared__ int holder[NS];
    const int lane = threadIdx.x;
    for (int k = lane; k < NS; k += 64) holder[k] = 0x7FFFFFFF;

    uint4 nextbuf = *(const uint4*)(top + (size_t)lane * 256);

    for (int g = 0; g < 24; ++g) {
        const int row = g * 64 + lane;
        uint4 buf = nextbuf;
        int pb = 0;                       // buf covers list positions [pb, pb+8)
        if (g + 1 < 24)
            nextbuf = *(const uint4*)(top + (size_t)(row + 64) * 256);
        int ptr = 0;
        int myc = -1;
        bool exhausted = false;
        bool active = true;

        for (int round = 0; round < 1024; ++round) {
            // --- scan & propose (active lanes with list remaining) ---
            if (active && !exhausted) {
                int c = -1;
                while (true) {
                    if (ptr >= 256) { exhausted = true; break; }
                    const int base = ptr & ~7;
                    if (base != pb) {
                        buf = *(const uint4*)(top + (size_t)row * 256 + base);
                        pb = base;
                    }
                    unsigned cc[8];
                    cc[0] = buf.x & 0xFFFFu; cc[1] = buf.x >> 16;
                    cc[2] = buf.y & 0xFFFFu; cc[3] = buf.y >> 16;
                    cc[4] = buf.z & 0xFFFFu; cc[5] = buf.z >> 16;
                    cc[6] = buf.w & 0xFFFFu; cc[7] = buf.w >> 16;
                    int h[8];
#pragma unroll
                    for (int k = 0; k < 8; ++k)
                        h[k] = holder[cc[k] < NS ? (int)cc[k] : 0];
                    const int k0 = ptr & 7;
                    unsigned qualm = 0, sentm = 0;
#pragma unroll
                    for (int k = 0; k < 8; ++k) {
                        if (k >= k0) {
                            if (cc[k] >= NS) sentm |= 1u << k;
                            else if (h[k] > row) qualm |= 1u << k;
                        }
                    }
                    const int fq = qualm ? __builtin_ctz(qualm) : 32;
                    const int fs = sentm ? __builtin_ctz(sentm) : 32;
                    if (fq < fs) { c = (int)cc[fq]; ptr = pb + fq; break; }
                    if (fs < 32) { exhausted = true; break; }
                    ptr = pb + 8;
                }
                if (c >= 0) { atomicMin(&holder[c], row); myc = c; }
            }

            // --- wave-cooperative fallback proposals for exhausted actives ---
            unsigned long long m = __ballot(active && exhausted);
            while (m) {
                const int l = __ffsll(m) - 1;
                m &= m - 1;
                const int rr = g * 64 + l;
                const float* __restrict__ Lr = L + (size_t)rr * NS;
                float bv = -FLT_MAX; int bi = NS;
#pragma unroll
                for (int k = 0; k < 24; ++k) {
                    const int col = lane + (k << 6);
                    const float v = Lr[col];
                    if (holder[col] > rr &&
                        (v > bv || (v == bv && col < bi))) { bv = v; bi = col; }
                }
#pragma unroll
                for (int o = 32; o >= 1; o >>= 1) {
                    const float ov = __shfl_xor(bv, o);
                    const int oi = __shfl_xor(bi, o);
                    if (ov > bv || (ov == bv && oi < bi)) { bv = ov; bi = oi; }
                }
                if (lane == l) { atomicMin(&holder[bi], rr); myc = bi; }
            }

            // --- settle check ---
            if (myc >= 0) active = (holder[myc] != row);
            if (__ballot(active) == 0) break;
        }
        assign[row] = myc;
    }
}

// ---------------- Kernel E: emit [1536][2][64] output ----------------
__global__ __launch_bounds__(128) void kE(const float* __restrict__ sat,
                                          const float* __restrict__ uav,
                                          const int* __restrict__ assign,
                                          float* __restrict__ out) {
    const int i = blockIdx.x;
    const int t = threadIdx.x;
    if (t < 64) out[(size_t)i * 128 + t] = sat[(size_t)i * DD + t];
    else        out[(size_t)i * 128 + t] = uav[(size_t)assign[i] * DD + (t - 64)];
}

extern "C" void kernel_launch(void* const* d_in, const int* in_sizes, int n_in,
                              void* d_out, int out_size, void* d_ws, size_t ws_size,
                              hipStream_t stream) {
    const float* sat = (const float*)d_in[0];
    const float* uav = (const float*)d_in[1];
    const float* W1  = (const float*)d_in[2];
    const float* b1  = (const float*)d_in[3];
    const float* W2  = (const float*)d_in[4];
    const float* b2  = (const float*)d_in[5];
    const float* W3  = (const float*)d_in[6];
    // d_in[7] = b3: sigmoid(x+b3) monotone in x — argmax unchanged.

    float* ws = (float*)d_ws;
    float* A   = ws + OFF_A;
    float* C2  = ws + OFF_C2;
    float* L   = ws + OFF_L;
    int* assign = (int*)(ws + OFF_AS);
    unsigned short* top = (unsigned short*)(ws + OFF_A);  // aliases A/C2 (dead after kB)

    hipLaunchKernelGGL(kA, dim3(NS), dim3(64), 0, stream, sat, uav, W1, b1, A, C2);
    hipLaunchKernelGGL(kB, dim3(NS / 4, NS / 256), dim3(256), 0, stream,
                       A, C2, W2, b2, W3, L);
    hipLaunchKernelGGL(kC, dim3(NS), dim3(256), 0, stream, L, top);
    hipLaunchKernelGGL(kD, dim3(1), dim3(64), 0, stream, L, top, assign);
    hipLaunchKernelGGL(kE, dim3(NS), dim3(128), 0, stream, sat, uav, assign,
                       (float*)d_out);
}

// Round 7
// 1584.948 us; speedup vs baseline: 1.9067x; 1.9067x over previous
//
#include <hip/hip_runtime.h>
#include <float.h>

#define NS 1536
#define DD 64

// ws layout (float elements)
static const size_t OFF_A  = 0;                          // A = h_sat + b1: [1536][64]
static const size_t OFF_C2 = 98304;                      // C2 = h_uav transposed [16][1536][4]
static const size_t OFF_L  = 196608;                     // logits [1536][1536]
static const size_t OFF_AS = 196608 + (size_t)NS * NS;   // int assign [1536]
// top_idx (ushort, 1536*256 = 786432 B) ALIASES the A/C2 region (dead after kB).

// ---------------- Kernel A: first-layer projections ----------------
__global__ __launch_bounds__(64) void kA(const float* __restrict__ sat,
                                         const float* __restrict__ uav,
                                         const float* __restrict__ W1,
                                         const float* __restrict__ b1,
                                         float* __restrict__ A,
                                         float* __restrict__ C2) {
    const int row = blockIdx.x;
    const int d = threadIdx.x;
    float accA = b1[d];
    float accC = 0.f;
    const float* __restrict__ satr = sat + row * DD;
    const float* __restrict__ uavr = uav + row * DD;
#pragma unroll 8
    for (int k = 0; k < DD; ++k) {
        accA = fmaf(satr[k], W1[k * DD + d], accA);
        accC = fmaf(uavr[k], W1[(DD + k) * DD + d], accC);
    }
    A[row * DD + d] = accA;
    C2[((size_t)(d >> 2) * NS + row) * 4 + (d & 3)] = accC;
}

// ---------------- Kernel B: all-pairs logits ----------------
__global__ __launch_bounds__(256) void kB(const float* __restrict__ A,
                                          const float* __restrict__ C2,
                                          const float* __restrict__ W2,
                                          const float* __restrict__ b2,
                                          const float* __restrict__ W3,
                                          float* __restrict__ L) {
    const int lane = threadIdx.x & 63;
    const int wave = threadIdx.x >> 6;
    const int i = __builtin_amdgcn_readfirstlane(blockIdx.x * 4 + wave);
    const int jbase = blockIdx.y * 256;
    const float* __restrict__ Ar = A + (size_t)i * DD;

    float u[4][32];
#pragma unroll
    for (int o = 0; o < 32; ++o) {
        const float b = b2[o];
        u[0][o] = b; u[1][o] = b; u[2][o] = b; u[3][o] = b;
    }

    const float4* __restrict__ C2v = (const float4*)C2;

    for (int d4 = 0; d4 < 16; ++d4) {
        float c[4][4];
#pragma unroll
        for (int p = 0; p < 4; ++p) {
            const float4 t = C2v[(size_t)d4 * NS + jbase + p * 64 + lane];
            c[p][0] = t.x; c[p][1] = t.y; c[p][2] = t.z; c[p][3] = t.w;
        }
#pragma unroll
        for (int dd = 0; dd < 4; ++dd) {
            const float a = Ar[d4 * 4 + dd];
            const float v0 = fmaxf(a + c[0][dd], 0.f);
            const float v1 = fmaxf(a + c[1][dd], 0.f);
            const float v2 = fmaxf(a + c[2][dd], 0.f);
            const float v3 = fmaxf(a + c[3][dd], 0.f);
            const float* __restrict__ w2r = W2 + (d4 * 4 + dd) * 32;
#pragma unroll
            for (int o = 0; o < 32; ++o) {
                const float w = w2r[o];
                u[0][o] = fmaf(v0, w, u[0][o]);
                u[1][o] = fmaf(v1, w, u[1][o]);
                u[2][o] = fmaf(v2, w, u[2][o]);
                u[3][o] = fmaf(v3, w, u[3][o]);
            }
        }
    }

#pragma unroll
    for (int p = 0; p < 4; ++p) {
        float acc = 0.f;
#pragma unroll
        for (int o = 0; o < 32; ++o)
            acc = fmaf(fmaxf(u[p][o], 0.f), W3[o], acc);
        L[(size_t)i * NS + jbase + p * 64 + lane] = acc;
    }
}

// ---------------- Kernel C: per-row sorted top-256 via 16-bit radix ----------------
// Output layout (lane-major for kD's uint2 loads):
//   top[row*256 + (r&63)*4 + (r>>6)] = col of rank r  (val desc, col asc).
__global__ __launch_bounds__(256) void kC(const float* __restrict__ L,
                                          unsigned short* __restrict__ top) {
    __shared__ int hist[256];
    __shared__ int suff[256];
    __shared__ float cv[1024];
    __shared__ int ci[1024];
    __shared__ int s_cnt, s_B0, s_base, s_B1;
    const int t = threadIdx.x;
    const int row = blockIdx.x;
    const float* __restrict__ Lr = L + (size_t)row * NS;

    top[row * 256 + t] = 0xFFFFu;   // sentinel (degenerate rows -> kD fallback)

    hist[t] = 0;
    if (t == 0) s_cnt = 0;
    __syncthreads();

    unsigned ub[6]; float fv[6];
#pragma unroll
    for (int k = 0; k < 6; ++k) {
        const float x = Lr[t + 256 * k];
        fv[k] = x;
        unsigned b = __float_as_uint(x);
        b = (b & 0x80000000u) ? ~b : (b | 0x80000000u);
        ub[k] = b;
        atomicAdd(&hist[b >> 24], 1);
    }
    __syncthreads();

    suff[t] = hist[t];
    __syncthreads();
    for (int off = 1; off < 256; off <<= 1) {
        const int v = (t + off < 256) ? suff[t + off] : 0;
        __syncthreads();
        suff[t] += v;
        __syncthreads();
    }
    if (suff[t] >= 256 && (t == 255 || suff[t + 1] < 256)) {
        s_B0 = t;
        s_base = (t == 255) ? 0 : suff[t + 1];
    }
    __syncthreads();
    const unsigned B0 = (unsigned)s_B0;
    const int base = s_base;

    hist[t] = 0;
    __syncthreads();
#pragma unroll
    for (int k = 0; k < 6; ++k)
        if ((ub[k] >> 24) == B0) atomicAdd(&hist[(ub[k] >> 16) & 255], 1);
    __syncthreads();
    suff[t] = hist[t];
    __syncthreads();
    for (int off = 1; off < 256; off <<= 1) {
        const int v = (t + off < 256) ? suff[t + off] : 0;
        __syncthreads();
        suff[t] += v;
        __syncthreads();
    }
    const int need = 256 - base;
    if (suff[t] >= need && (t == 255 || suff[t + 1] < need)) s_B1 = t;
    __syncthreads();
    const unsigned B1 = (unsigned)s_B1;
    const int m = base + suff[B1];
    if (m > 1024) return;

#pragma unroll
    for (int k = 0; k < 6; ++k) {
        const unsigned hi = ub[k] >> 24;
        const unsigned mid = (ub[k] >> 16) & 255u;
        if (hi > B0 || (hi == B0 && mid >= B1)) {
            const int pos = atomicAdd(&s_cnt, 1);
            cv[pos] = fv[k];
            ci[pos] = t + 256 * k;
        }
    }
    __syncthreads();

    for (int e = t; e < m; e += 256) {
        const float v = cv[e]; const int id = ci[e];
        int r = 0;
        for (int s2 = 0; s2 < m; ++s2) {
            const float vs = cv[s2];
            if (vs > v || (vs == v && ci[s2] < id)) ++r;
        }
        if (r < 256) top[row * 256 + (r & 63) * 4 + (r >> 6)] = (unsigned short)id;
    }
}

// ---------------- Kernel D: serial greedy, register-resident avail flags ----------------
// Single wave. 8 resident rows, 4 candidates/lane each, avail flags F* kept
// EXACT in registers: initialized once per group from used_s (off-chain), then
// updated per pick via j-broadcast compares. Steady-state per-row chain:
// 4 v_cmp ballots -> scalar select -> readlane -> 8 VALU flag updates. No LDS,
// no global, no shfl on the chain. used_s maintained (lane0 ds_write) for the
// group-boundary inits and the exact fallback (same-wave DS ops are in-order).
__global__ __launch_bounds__(64) void kD(const float* __restrict__ L,
                                         const unsigned short* __restrict__ top,
                                         int* __restrict__ assign) {
    __shared__ int used_s[NS];
    __shared__ int assign_s[NS];
    const int lane = threadIdx.x;
    for (int k = lane; k < NS; k += 64) used_s[k] = 0;
    __syncthreads();

    const uint2* __restrict__ T = (const uint2*)top;   // T[row*64+lane]

    int C0[8], C1[8], C2r[8], C3[8];   // unpacked candidates (rows base..base+7)
    int F0[8], F1[8], F2[8], F3[8];    // avail flags (0/1)

#pragma unroll
    for (int q = 0; q < 8; ++q) {
        const uint2 u = T[q * 64 + lane];
        C0[q] = (int)(u.x & 0xFFFFu); C1[q] = (int)(u.x >> 16);
        C2r[q] = (int)(u.y & 0xFFFFu); C3[q] = (int)(u.y >> 16);
        F0[q] = C0[q] < NS; F1[q] = C1[q] < NS;
        F2[q] = C2r[q] < NS; F3[q] = C3[q] < NS;
    }

    for (int base = 0; base < NS; base += 8) {
        // issue next group's candidate loads (rows base+8..base+15)
        uint2 nb[8];
#pragma unroll
        for (int q = 0; q < 8; ++q) {
            int r = base + 8 + q;
            r = (r < NS) ? r : (NS - 1);
            nb[q] = T[(size_t)r * 64 + lane];
        }

#pragma unroll
        for (int q = 0; q < 8; ++q) {
            const int i = base + q;
            int j;
            const unsigned long long b0 = __ballot(F0[q] != 0);
            const unsigned long long b1 = __ballot(F1[q] != 0);
            const unsigned long long b2 = __ballot(F2[q] != 0);
            const unsigned long long b3 = __ballot(F3[q] != 0);
            if (b0)      j = __builtin_amdgcn_readlane(C0[q], __ffsll(b0) - 1);
            else if (b1) j = __builtin_amdgcn_readlane(C1[q], __ffsll(b1) - 1);
            else if (b2) j = __builtin_amdgcn_readlane(C2r[q], __ffsll(b2) - 1);
            else if (b3) j = __builtin_amdgcn_readlane(C3[q], __ffsll(b3) - 1);
            else {
                // exact fallback: masked argmax over used_s==0 (contains all picks < i)
                const float* __restrict__ Lr = L + (size_t)i * NS;
                float v[24];
#pragma unroll
                for (int k = 0; k < 24; ++k) v[k] = Lr[lane + (k << 6)];
                int uf[24];
#pragma unroll
                for (int k = 0; k < 24; ++k) uf[k] = used_s[lane + (k << 6)];
                float bv = -FLT_MAX; int bi = NS;
#pragma unroll
                for (int k = 0; k < 24; ++k) {
                    const int col = lane + (k << 6);
                    if (uf[k] == 0 && (v[k] > bv || (v[k] == bv && col < bi))) {
                        bv = v[k]; bi = col;
                    }
                }
#pragma unroll
                for (int o = 32; o >= 1; o >>= 1) {
                    const float ov = __shfl_xor(bv, o);
                    const int oi = __shfl_xor(bi, o);
                    if (ov > bv || (ov == bv && oi < bi)) { bv = ov; bi = oi; }
                }
                j = bi;
            }

            if (lane == 0) { used_s[j] = 1; assign_s[i] = j; }

            // apply pick to remaining resident rows (next row first: on-chain)
#pragma unroll
            for (int p = q + 1; p < 8; ++p) {
                F0[p] = (C0[p] == j) ? 0 : F0[p];
                F1[p] = (C1[p] == j) ? 0 : F1[p];
                F2[p] = (C2r[p] == j) ? 0 : F2[p];
                F3[p] = (C3[p] == j) ? 0 : F3[p];
            }
        }

        // rotate next group in; init flags from used_s snapshot (has all picks <= base+7)
#pragma unroll
        for (int q = 0; q < 8; ++q) {
            const uint2 u = nb[q];
            C0[q] = (int)(u.x & 0xFFFFu); C1[q] = (int)(u.x >> 16);
            C2r[q] = (int)(u.y & 0xFFFFu); C3[q] = (int)(u.y >> 16);
            F0[q] = (C0[q] < NS) ? (used_s[C0[q]] == 0) : 0;
            F1[q] = (C1[q] < NS) ? (used_s[C1[q]] == 0) : 0;
            F2[q] = (C2r[q] < NS) ? (used_s[C2r[q]] == 0) : 0;
            F3[q] = (C3[q] < NS) ? (used_s[C3[q]] == 0) : 0;
        }
    }

    for (int k = lane; k < NS; k += 64) assign[k] = assign_s[k];
}

// ---------------- Kernel E: emit [1536][2][64] output ----------------
__global__ __launch_bounds__(128) void kE(const float* __restrict__ sat,
                                          const float* __restrict__ uav,
                                          const int* __restrict__ assign,
                                          float* __restrict__ out) {
    const int i = blockIdx.x;
    const int t = threadIdx.x;
    if (t < 64) out[(size_t)i * 128 + t] = sat[(size_t)i * DD + t];
    else        out[(size_t)i * 128 + t] = uav[(size_t)assign[i] * DD + (t - 64)];
}

extern "C" void kernel_launch(void* const* d_in, const int* in_sizes, int n_in,
                              void* d_out, int out_size, void* d_ws, size_t ws_size,
                              hipStream_t stream) {
    const float* sat = (const float*)d_in[0];
    const float* uav = (const float*)d_in[1];
    const float* W1  = (const float*)d_in[2];
    const float* b1  = (const float*)d_in[3];
    const float* W2  = (const float*)d_in[4];
    const float* b2  = (const float*)d_in[5];
    const float* W3  = (const float*)d_in[6];
    // d_in[7] = b3: sigmoid(x+b3) monotone in x — argmax unchanged.

    float* ws = (float*)d_ws;
    float* A   = ws + OFF_A;
    float* C2  = ws + OFF_C2;
    float* L   = ws + OFF_L;
    int* assign = (int*)(ws + OFF_AS);
    unsigned short* top = (unsigned short*)(ws + OFF_A);  // aliases A/C2 (dead after kB)

    hipLaunchKernelGGL(kA, dim3(NS), dim3(64), 0, stream, sat, uav, W1, b1, A, C2);
    hipLaunchKernelGGL(kB, dim3(NS / 4, NS / 256), dim3(256), 0, stream,
                       A, C2, W2, b2, W3, L);
    hipLaunchKernelGGL(kC, dim3(NS), dim3(256), 0, stream, L, top);
    hipLaunchKernelGGL(kD, dim3(1), dim3(64), 0, stream, L, top, assign);
    hipLaunchKernelGGL(kE, dim3(NS), dim3(128), 0, stream, sat, uav, assign,
                       (float*)d_out);
}